// Round 1
// baseline (81.246 us; speedup 1.0000x reference)
//
#include <hip/hip_runtime.h>

#define VOCAB 512
#define W 24
#define ROWS_PER_BLOCK 4   // 4 waves of 64 lanes, one row per wave

__global__ __launch_bounds__(256) void fofe_kernel(
    const int*   __restrict__ sents,    // [nrows * W] int32 char ids (0 = pad)
    const int*   __restrict__ lengths,  // [nlen]
    const float* __restrict__ alpha_p,  // [1]
    float*       __restrict__ out,      // [nrows * VOCAB] then [nlen] lengths-as-f32
    int nrows, int nlen)
{
    __shared__ float lds[ROWS_PER_BLOCK][VOCAB];   // 8 KB / block

    const int wave = threadIdx.x >> 6;
    const int lane = threadIdx.x & 63;
    const int row  = blockIdx.x * ROWS_PER_BLOCK + wave;
    const bool row_ok = (row < nrows);

    // Output 1: lengths pass-through (stored as float32 in the flat output).
    if (blockIdx.x == 0 && threadIdx.x < nlen) {
        out[(size_t)nrows * VOCAB + threadIdx.x] = (float)lengths[threadIdx.x];
    }

    // --- zero the per-wave histogram (2 x ds_write_b128 per lane) ---
    float*  bins  = lds[wave];
    float4* bins4 = (float4*)bins;
    const float4 z = make_float4(0.f, 0.f, 0.f, 0.f);
    bins4[lane]      = z;
    bins4[lane + 64] = z;
    __syncthreads();

    // --- load chars, compute decay weights, scatter ---
    int c = 0;
    if (row_ok && lane < W) c = sents[(size_t)row * W + lane];

    // suffix count: # non-pad chars strictly after this lane in the 24-window
    unsigned long long mask = __ballot(c != 0);

    if (c != 0) {
        int suffix = __popcll(mask >> (lane + 1));   // lane < 24 here, shift <= 24
        const float alpha = alpha_p[0];
        // alpha^suffix by binary exponentiation (suffix in [0,23], 5 bits)
        float acc = 1.0f, p = alpha;
        #pragma unroll
        for (int b = 0; b < 5; ++b) {
            if (suffix & (1 << b)) acc *= p;
            p *= p;
        }
        atomicAdd(&bins[c], acc);   // ds_add_f32; duplicates within row handled
    }
    __syncthreads();

    // --- coalesced dump: 2 x global_store_dwordx4 per lane ---
    if (row_ok) {
        float4* out4 = (float4*)(out + (size_t)row * VOCAB);
        out4[lane]      = bins4[lane];
        out4[lane + 64] = bins4[lane + 64];
    }
}

extern "C" void kernel_launch(void* const* d_in, const int* in_sizes, int n_in,
                              void* d_out, int out_size, void* d_ws, size_t ws_size,
                              hipStream_t stream) {
    const int*   sents   = (const int*)d_in[0];
    const int*   lengths = (const int*)d_in[1];
    const float* alpha   = (const float*)d_in[2];
    float*       out     = (float*)d_out;

    const int nrows = in_sizes[0] / W;   // 64*512 = 32768
    const int nlen  = in_sizes[1];       // 64

    const int blocks = (nrows + ROWS_PER_BLOCK - 1) / ROWS_PER_BLOCK;  // 8192
    fofe_kernel<<<blocks, 256, 0, stream>>>(sents, lengths, alpha, out, nrows, nlen);
}

// Round 2
// 79.458 us; speedup vs baseline: 1.0225x; 1.0225x over previous
//
#include <hip/hip_runtime.h>

#define VOCAB 512
#define W 24
#define WAVES_PER_BLOCK 4   // 256 threads = 4 waves, one row per wave per iteration

__global__ __launch_bounds__(256, 8) void fofe_kernel(
    const int*   __restrict__ sents,    // [nrows * W] int32 char ids (0 = pad)
    const int*   __restrict__ lengths,  // [nlen]
    const float* __restrict__ alpha_p,  // [1]
    float*       __restrict__ out,      // [nrows * VOCAB] then [nlen] lengths-as-f32
    int nrows, int nlen)
{
    // One wave-private 512-float histogram per wave. No inter-wave sharing ->
    // no __syncthreads needed anywhere; in-wave DS ordering + lgkmcnt suffices.
    __shared__ float lds[WAVES_PER_BLOCK][VOCAB];   // 8 KB / block

    const int wave  = threadIdx.x >> 6;
    const int lane  = threadIdx.x & 63;
    const int gwave = blockIdx.x * WAVES_PER_BLOCK + wave;
    const int nw    = gridDim.x * WAVES_PER_BLOCK;
    const float alpha = alpha_p[0];

    // Output 1: lengths pass-through (float32 in the flat output tail).
    if (blockIdx.x == 0 && threadIdx.x < nlen) {
        out[(size_t)nrows * VOCAB + threadIdx.x] = (float)lengths[threadIdx.x];
    }

    float*  bins  = lds[wave];
    float4* bins4 = (float4*)bins;

    for (int row = gwave; row < nrows; row += nw) {
        // zero the wave-private histogram (2 x ds_write_b128 per lane)
        const float4 z = make_float4(0.f, 0.f, 0.f, 0.f);
        bins4[lane]      = z;
        bins4[lane + 64] = z;

        // load chars (lanes 0..23), compute decay weight, scatter
        int c = 0;
        if (lane < W) c = sents[(size_t)row * W + lane];

        unsigned long long mask = __ballot(c != 0);
        if (c != 0) {
            int suffix = __popcll(mask >> (lane + 1));  // non-pad chars after k
            // alpha^suffix by binary exponentiation (suffix in [0,23])
            float acc = 1.0f, p = alpha;
            #pragma unroll
            for (int b = 0; b < 5; ++b) {
                if (suffix & (1 << b)) acc *= p;
                p *= p;
            }
            atomicAdd(&bins[c], acc);   // ds_add_f32, wave-private bins
        }

        // drain the ds_add before readback; "memory" stops compiler reordering
        asm volatile("s_waitcnt lgkmcnt(0)" ::: "memory");

        // coalesced dump: 2 x global_store_dwordx4 per lane (1 KB / instr / wave)
        float4* out4 = (float4*)(out + (size_t)row * VOCAB);
        out4[lane]      = bins4[lane];
        out4[lane + 64] = bins4[lane + 64];
    }
}

extern "C" void kernel_launch(void* const* d_in, const int* in_sizes, int n_in,
                              void* d_out, int out_size, void* d_ws, size_t ws_size,
                              hipStream_t stream) {
    const int*   sents   = (const int*)d_in[0];
    const int*   lengths = (const int*)d_in[1];
    const float* alpha   = (const float*)d_in[2];
    float*       out     = (float*)d_out;

    const int nrows = in_sizes[0] / W;   // 64*512 = 32768
    const int nlen  = in_sizes[1];       // 64

    // 2048 blocks = 8 blocks/CU of 4 waves = full 32-wave/CU residency;
    // each wave grid-strides over ~4 rows.
    int blocks = 2048;
    int max_blocks = (nrows + WAVES_PER_BLOCK - 1) / WAVES_PER_BLOCK;
    if (blocks > max_blocks) blocks = max_blocks;
    fofe_kernel<<<blocks, 256, 0, stream>>>(sents, lengths, alpha, out, nrows, nlen);
}